// Round 3
// baseline (308.259 us; speedup 1.0000x reference)
//
#include <hip/hip_runtime.h>
#include <math.h>

#define NI 100000
#define NO 50000
#define NE 100000
#define NB (NI + NO)          // 150000 combined dst bins
#define TOTE (2 * NE)         // 200000

// ---- ws layout (4B units) ----
#define OFF_WRT_OI   0         // 1024
#define OFF_WRT_IO   1024      // 1024
#define OFF_Y2Z2     2048      // 600000
#define OFF_SCANNED  602048    // 150016 ints
#define OFF_BLOCKSUM 752064    // 640 ints
#define OFF_BLOCKPREF 752704   // 640 ints
#define OFF_SORTED   753344    // 200000 ints
#define OFF_DSTS     953344    // 200000 ints
#define OFF_ACC      1153344   // 4800000 floats (zeroed in fused kernel)
#define OFF_CNT      5953344   // 150016 ints (memset)
#define OFF_CNT2     6103360   // 150016 ints (memset)
#define OFF_YIND     6253376   // bf16 100000*288 ushort = 14400000 float-slots
#define OFF_YORG     20653376  // bf16 50000*288 ushort  = 7200000 float-slots
// total 27,853,376 floats = 111.4 MB

static constexpr int B_EDGE = (NE + 255) / 256;    // 391
static constexpr int B_IND  = (NI + 255) / 256;    // 391
static constexpr int B_ORG  = (NO + 255) / 256;    // 196
static constexpr int SCAN_BLOCKS = (NB + 255) / 256;  // 586

// fused-kernel block ranges
static constexpr int FB_PRE_I = 0;                  // [0, 391)   Y for indivi (io srcs)
static constexpr int FB_PRE_O = 391;                // [391, 587) Y for org (oi srcs)
static constexpr int FB_HIST  = 587;                // [587, 1369) dst histogram
static constexpr int FB_ZERO  = 1369;               // [1369, 1625) zero acc
static constexpr int FB_PREP  = 1625;               // [1625, 1633) WrT transposes
static constexpr int FB_TOTAL = 1633;

__device__ __forceinline__ float sigmoidf_fast(float x) {
    return 1.0f / (1.0f + __expf(-x));
}
__device__ __forceinline__ unsigned short f2bf(float f) {
    unsigned int u = __float_as_uint(f);
    unsigned int r = (u + 0x7FFFu + ((u >> 16) & 1u)) >> 16;
    return (unsigned short)r;
}
__device__ __forceinline__ float bflo(unsigned int u) { return __uint_as_float(u << 16); }
__device__ __forceinline__ float bfhi(unsigned int u) { return __uint_as_float(u & 0xFFFF0000u); }

// ---------------------------------------------------------------- per-src Y precompute
__device__ __forceinline__ void pre_node(
    const float* __restrict__ x, const float* __restrict__ Wm, const float* __restrict__ bm,
    unsigned short* __restrict__ yout)
{
    float xr[32];
    const float4* xp = (const float4*)x;
    #pragma unroll
    for (int q = 0; q < 8; q++) {
        float4 v = xp[q];
        xr[q * 4 + 0] = v.x; xr[q * 4 + 1] = v.y; xr[q * 4 + 2] = v.z; xr[q * 4 + 3] = v.w;
    }
    // rows a=0..7 from Wm, row a=8 from bm.  Y[a][o] = sum_i x[i]*W[a,i,o]
    for (int a = 0; a < 9; a++) {
        const float* wa = (a < 8) ? (Wm + a * 1024) : bm;
        #pragma unroll
        for (int og = 0; og < 4; og++) {
            float acc8[8];
            #pragma unroll
            for (int j = 0; j < 8; j++) acc8[j] = 0.0f;
            #pragma unroll 8
            for (int i = 0; i < 32; i++) {
                const float* w = wa + i * 32 + og * 8;   // wave-uniform -> scalar loads
                #pragma unroll
                for (int j = 0; j < 8; j++) acc8[j] = fmaf(xr[i], w[j], acc8[j]);
            }
            uint4 pk;
            pk.x = (unsigned)f2bf(acc8[0]) | ((unsigned)f2bf(acc8[1]) << 16);
            pk.y = (unsigned)f2bf(acc8[2]) | ((unsigned)f2bf(acc8[3]) << 16);
            pk.z = (unsigned)f2bf(acc8[4]) | ((unsigned)f2bf(acc8[5]) << 16);
            pk.w = (unsigned)f2bf(acc8[6]) | ((unsigned)f2bf(acc8[7]) << 16);
            *(uint4*)(yout + a * 32 + og * 8) = pk;
        }
    }
}

// ---------------------------------------------------------------- fused front-end
__global__ __launch_bounds__(256) void k_front(
    const float* __restrict__ x_ind, const float* __restrict__ x_org,
    const float* __restrict__ Wm_oi, const float* __restrict__ bm_oi, const float* __restrict__ Wr_oi,
    const float* __restrict__ Wm_io, const float* __restrict__ bm_io, const float* __restrict__ Wr_io,
    const int* __restrict__ dst_oi, const int* __restrict__ dst_io,
    float* __restrict__ ws, int* __restrict__ cnt)
{
    int b = blockIdx.x;
    if (b < FB_PRE_O) {                      // Y for indivi nodes (srcs of io relation)
        int n = b * 256 + threadIdx.x;
        if (n >= NI) return;
        unsigned short* yout = (unsigned short*)(ws + OFF_YIND) + (size_t)n * 288;
        pre_node(x_ind + n * 32, Wm_io, bm_io, yout);
    } else if (b < FB_HIST) {                // Y for org nodes (srcs of oi relation)
        int n = (b - FB_PRE_O) * 256 + threadIdx.x;
        if (n >= NO) return;
        unsigned short* yout = (unsigned short*)(ws + OFF_YORG) + (size_t)n * 288;
        pre_node(x_org + n * 32, Wm_oi, bm_oi, yout);
    } else if (b < FB_ZERO) {                // dst histogram
        int u = b - FB_HIST;
        bool is_io = u >= B_EDGE;
        int e = (is_io ? (u - B_EDGE) : u) * 256 + threadIdx.x;
        if (e >= NE) return;
        int cd = is_io ? (NI + dst_io[e]) : dst_oi[e];
        atomicAdd(&cnt[cd], 1);
    } else if (b < FB_PREP) {                // zero acc
        int idx = (b - FB_ZERO) * 256 + threadIdx.x;   // [0, 65536)
        float4* a4 = (float4*)(ws + OFF_ACC);
        for (int q = idx; q < 1200000; q += 65536)
            a4[q] = make_float4(0.f, 0.f, 0.f, 0.f);
    } else {                                 // WrT transposes
        int u = (b - FB_PREP) * 256 + threadIdx.x;
        if (u < 1024)       ws[OFF_WRT_OI + u] = Wr_oi[(u & 31) * 32 + (u >> 5)];
        else if (u < 2048)  { int v = u - 1024; ws[OFF_WRT_IO + v] = Wr_io[(v & 31) * 32 + (v >> 5)]; }
    }
}

// ---------------------------------------------------------------- block-level exclusive scan
__global__ __launch_bounds__(256) void k_scan_block(
    const int* __restrict__ cnt, int* __restrict__ scanned, int* __restrict__ blocksum)
{
    int d = blockIdx.x * 256 + threadIdx.x;
    int v = (d < NB) ? cnt[d] : 0;
    int lane = threadIdx.x & 63, wv = threadIdx.x >> 6;
    int s = v;
    #pragma unroll
    for (int off = 1; off < 64; off <<= 1) {
        int t = __shfl_up(s, off);
        if (lane >= off) s += t;
    }
    __shared__ int wsum[4];
    if (lane == 63) wsum[wv] = s;
    __syncthreads();
    int add = 0;
    for (int w = 0; w < wv; w++) add += wsum[w];
    int incl = s + add;
    scanned[d] = incl - v;
    if (threadIdx.x == 255) blocksum[blockIdx.x] = incl;
}

__global__ __launch_bounds__(1024) void k_scan_top(
    const int* __restrict__ blocksum, int* __restrict__ blockpref)
{
    __shared__ int L[1024];
    int t = threadIdx.x;
    int v = (t < SCAN_BLOCKS) ? blocksum[t] : 0;
    L[t] = v;
    __syncthreads();
    for (int off = 1; off < 1024; off <<= 1) {
        int u = (t >= off) ? L[t - off] : 0;
        __syncthreads();
        L[t] += u;
        __syncthreads();
    }
    if (t < SCAN_BLOCKS) blockpref[t] = L[t] - v;
}

__global__ __launch_bounds__(256) void k_scatter(
    const int* __restrict__ dst_oi, const int* __restrict__ dst_io,
    const int* __restrict__ scanned, const int* __restrict__ blockpref,
    int* __restrict__ cnt2, int* __restrict__ sorted_eid, int* __restrict__ dstsorted)
{
    bool is_io = blockIdx.x >= B_EDGE;
    int e = (is_io ? (blockIdx.x - B_EDGE) : blockIdx.x) * 256 + threadIdx.x;
    if (e >= NE) return;
    int cd = is_io ? (NI + dst_io[e]) : dst_oi[e];
    int base = scanned[cd] + blockpref[cd >> 8];
    int pos = base + atomicAdd(&cnt2[cd], 1);
    sorted_eid[pos] = e;
    dstsorted[pos] = cd;
}

// ---------------------------------------------------------------- layer-1 edge messages (factorized)
__global__ __launch_bounds__(256) void k_edge(
    const int* __restrict__ src_oi, const float* __restrict__ attr_oi,
    const int* __restrict__ src_io, const float* __restrict__ attr_io,
    const unsigned short* __restrict__ Yind, const unsigned short* __restrict__ Yorg,
    const int* __restrict__ sorted_eid, const int* __restrict__ dstsorted,
    float* __restrict__ acc)
{
    __shared__ float stage[256 * 36];
    bool is_io = blockIdx.x >= B_EDGE;
    int blockStart = is_io ? (NE + (blockIdx.x - B_EDGE) * 256) : (blockIdx.x * 256);
    int relEnd = is_io ? TOTE : NE;
    int p = blockStart + (int)threadIdx.x;
    bool act = p < relEnd;

    const int*   srcA  = is_io ? src_io : src_oi;
    const float* attrA = is_io ? attr_io : attr_oi;
    const unsigned short* Yb = is_io ? Yind : Yorg;

    int cd = -1;
    float msg[32];
    if (act) {
        cd = dstsorted[p];
        int e = sorted_eid[p];
        int s = srcA[e];
        float ar[8];
        {
            const float4* ap = (const float4*)(attrA + e * 8);
            float4 v0 = ap[0], v1 = ap[1];
            ar[0] = v0.x; ar[1] = v0.y; ar[2] = v0.z; ar[3] = v0.w;
            ar[4] = v1.x; ar[5] = v1.y; ar[6] = v1.z; ar[7] = v1.w;
        }
        #pragma unroll
        for (int o = 0; o < 32; o++) msg[o] = 0.0f;
        const uint4* yrow = (const uint4*)(Yb + (size_t)s * 288);
        #pragma unroll
        for (int a = 0; a < 9; a++) {
            float c = (a < 8) ? ar[a] : 1.0f;
            #pragma unroll
            for (int g = 0; g < 4; g++) {
                uint4 v = yrow[a * 4 + g];
                int ob = g * 8;
                msg[ob + 0] = fmaf(c, bflo(v.x), msg[ob + 0]);
                msg[ob + 1] = fmaf(c, bfhi(v.x), msg[ob + 1]);
                msg[ob + 2] = fmaf(c, bflo(v.y), msg[ob + 2]);
                msg[ob + 3] = fmaf(c, bfhi(v.y), msg[ob + 3]);
                msg[ob + 4] = fmaf(c, bflo(v.z), msg[ob + 4]);
                msg[ob + 5] = fmaf(c, bfhi(v.z), msg[ob + 5]);
                msg[ob + 6] = fmaf(c, bflo(v.w), msg[ob + 6]);
                msg[ob + 7] = fmaf(c, bfhi(v.w), msg[ob + 7]);
            }
        }
        float4* srow = (float4*)(stage + threadIdx.x * 36);
        #pragma unroll
        for (int q = 0; q < 8; q++)
            srow[q] = make_float4(msg[q * 4 + 0], msg[q * 4 + 1], msg[q * 4 + 2], msg[q * 4 + 3]);
    }
    __syncthreads();

    bool head = act && (p == blockStart || dstsorted[p - 1] != cd);
    if (head) {
        int blockEnd = min(blockStart + 256, relEnd);
        int q = p + 1;
        while (q < blockEnd && dstsorted[q] == cd) {
            const float4* rrow = (const float4*)(stage + (q - blockStart) * 36);
            #pragma unroll
            for (int j = 0; j < 8; j++) {
                float4 v = rrow[j];
                msg[j * 4 + 0] += v.x; msg[j * 4 + 1] += v.y;
                msg[j * 4 + 2] += v.z; msg[j * 4 + 3] += v.w;
            }
            q++;
        }
        bool openR = (q == blockEnd) && (q < TOTE) && (dstsorted[q] == cd);
        bool openL = (p == blockStart) && (p > 0) && (dstsorted[p - 1] == cd);
        float* dp = acc + (size_t)cd * 32;
        if (openL || openR) {
            #pragma unroll
            for (int o = 0; o < 32; o++) atomicAdd(dp + o, msg[o]);
        } else {
            float4* dp4 = (float4*)dp;
            #pragma unroll
            for (int j = 0; j < 8; j++)
                dp4[j] = make_float4(msg[j * 4 + 0], msg[j * 4 + 1], msg[j * 4 + 2], msg[j * 4 + 3]);
        }
    }
}

// ---------------------------------------------------------------- finish layer 1 + prep layer 2
__global__ __launch_bounds__(256) void k_finish(
    const float* __restrict__ x_ind, const float* __restrict__ x_org,
    const float* __restrict__ ws, const float* __restrict__ acc,
    const float* __restrict__ b_oi, const float* __restrict__ b_io,
    const float* __restrict__ Wm2, const float* __restrict__ bm2,
    const float* __restrict__ Wr2, const float* __restrict__ b2,
    float* __restrict__ y2z2, float* __restrict__ out)
{
    bool is_org = blockIdx.x >= B_IND;
    int n = (is_org ? (blockIdx.x - B_IND) : blockIdx.x) * 256 + threadIdx.x;
    int N = is_org ? NO : NI;
    if (n >= N) return;
    int cd = is_org ? (NI + n) : n;

    const float* x    = is_org ? x_org : x_ind;
    const float* WrT  = ws + (is_org ? OFF_WRT_IO : OFF_WRT_OI);
    const float* bias = is_org ? b_io : b_oi;

    float xr[32];
    const float4* xp = (const float4*)(x + n * 32);
    #pragma unroll
    for (int q = 0; q < 8; q++) {
        float4 v = xp[q];
        xr[q * 4 + 0] = v.x; xr[q * 4 + 1] = v.y; xr[q * 4 + 2] = v.z; xr[q * 4 + 3] = v.w;
    }
    float h[32];
    const float4* aprow = (const float4*)(acc + (size_t)cd * 32);
    #pragma unroll
    for (int q = 0; q < 8; q++) {
        float4 v = aprow[q];
        h[q * 4 + 0] = v.x; h[q * 4 + 1] = v.y; h[q * 4 + 2] = v.z; h[q * 4 + 3] = v.w;
    }
    #pragma unroll 4
    for (int o = 0; o < 32; o++) {
        float s = bias[o] + h[o];
        #pragma unroll
        for (int i = 0; i < 32; i++) s = fmaf(xr[i], WrT[o * 32 + i], s);
        h[o] = sigmoidf_fast(s);
    }
    if (!is_org) {
        float s = b2[0];
        #pragma unroll
        for (int i = 0; i < 32; i++) s = fmaf(h[i], Wr2[i], s);
        out[n] = s;
    } else {
        float z2 = 0.0f;
        #pragma unroll
        for (int i = 0; i < 32; i++) z2 = fmaf(h[i], bm2[i], z2);
        float* yz = y2z2 + n * 12;
        yz[0] = z2;
        #pragma unroll
        for (int a = 0; a < 8; a++) {
            float s = 0.0f;
            #pragma unroll
            for (int i = 0; i < 32; i++) s = fmaf(h[i], Wm2[a * 32 + i], s);
            yz[1 + a] = s;
        }
    }
}

// ---------------------------------------------------------------- layer 2: CSR gather per indivi node
__global__ __launch_bounds__(256) void k_out(
    const int* __restrict__ src_oi, const float* __restrict__ attr_oi,
    const int* __restrict__ scanned, const int* __restrict__ blockpref,
    const int* __restrict__ sorted_eid, const float* __restrict__ y2z2,
    float* __restrict__ out)
{
    int d = blockIdx.x * 256 + threadIdx.x;
    if (d >= NI) return;
    int base = scanned[d] + blockpref[d >> 8];
    int next = scanned[d + 1] + blockpref[(d + 1) >> 8];
    float t = out[d];
    for (int p = base; p < next; p++) {
        int e = sorted_eid[p];
        int s = src_oi[e];
        const float* yz = y2z2 + s * 12;
        const float4* ap = (const float4*)(attr_oi + e * 8);
        float4 a0 = ap[0], a1 = ap[1];
        float m = yz[0];
        m = fmaf(a0.x, yz[1], m); m = fmaf(a0.y, yz[2], m);
        m = fmaf(a0.z, yz[3], m); m = fmaf(a0.w, yz[4], m);
        m = fmaf(a1.x, yz[5], m); m = fmaf(a1.y, yz[6], m);
        m = fmaf(a1.z, yz[7], m); m = fmaf(a1.w, yz[8], m);
        t += m;
    }
    out[d] = sigmoidf_fast(t);
}

// ---------------------------------------------------------------- launch
extern "C" void kernel_launch(void* const* d_in, const int* in_sizes, int n_in,
                              void* d_out, int out_size, void* d_ws, size_t ws_size,
                              hipStream_t stream)
{
    const float* x_ind   = (const float*)d_in[0];
    const float* x_org   = (const float*)d_in[1];
    const int*   src_oi  = (const int*)d_in[2];
    const int*   dst_oi  = (const int*)d_in[3];
    const float* attr_oi = (const float*)d_in[4];
    const int*   src_io  = (const int*)d_in[5];
    const int*   dst_io  = (const int*)d_in[6];
    const float* attr_io = (const float*)d_in[7];
    const float* Wm_oi   = (const float*)d_in[8];
    const float* bm_oi   = (const float*)d_in[9];
    const float* Wr_oi   = (const float*)d_in[10];
    const float* b_oi    = (const float*)d_in[11];
    const float* Wm_io   = (const float*)d_in[12];
    const float* bm_io   = (const float*)d_in[13];
    const float* Wr_io   = (const float*)d_in[14];
    const float* b_io    = (const float*)d_in[15];
    const float* Wm2     = (const float*)d_in[16];
    const float* bm2     = (const float*)d_in[17];
    const float* Wr2     = (const float*)d_in[18];
    const float* b2      = (const float*)d_in[19];

    float* ws        = (float*)d_ws;
    float* y2z2      = ws + OFF_Y2Z2;
    int*   scanned   = (int*)(ws + OFF_SCANNED);
    int*   blocksum  = (int*)(ws + OFF_BLOCKSUM);
    int*   blockpref = (int*)(ws + OFF_BLOCKPREF);
    int*   sorted    = (int*)(ws + OFF_SORTED);
    int*   dsts      = (int*)(ws + OFF_DSTS);
    float* acc       = ws + OFF_ACC;
    int*   cnt       = (int*)(ws + OFF_CNT);
    int*   cnt2      = (int*)(ws + OFF_CNT2);
    const unsigned short* Yind = (const unsigned short*)(ws + OFF_YIND);
    const unsigned short* Yorg = (const unsigned short*)(ws + OFF_YORG);
    float* out       = (float*)d_out;

    // zero cnt + cnt2 (contiguous)
    hipMemsetAsync(ws + OFF_CNT, 0, (size_t)(2 * 150016) * 4, stream);

    k_front<<<FB_TOTAL, 256, 0, stream>>>(
        x_ind, x_org, Wm_oi, bm_oi, Wr_oi, Wm_io, bm_io, Wr_io,
        dst_oi, dst_io, ws, cnt);

    k_scan_block<<<SCAN_BLOCKS, 256, 0, stream>>>(cnt, scanned, blocksum);

    k_scan_top<<<1, 1024, 0, stream>>>(blocksum, blockpref);

    k_scatter<<<2 * B_EDGE, 256, 0, stream>>>(
        dst_oi, dst_io, scanned, blockpref, cnt2, sorted, dsts);

    k_edge<<<2 * B_EDGE, 256, 0, stream>>>(
        src_oi, attr_oi, src_io, attr_io, Yind, Yorg, sorted, dsts, acc);

    k_finish<<<B_IND + B_ORG, 256, 0, stream>>>(
        x_ind, x_org, ws, acc, b_oi, b_io, Wm2, bm2, Wr2, b2, y2z2, out);

    k_out<<<B_IND, 256, 0, stream>>>(
        src_oi, attr_oi, scanned, blockpref, sorted, y2z2, out);
}

// Round 4
// 184.226 us; speedup vs baseline: 1.6733x; 1.6733x over previous
//
#include <hip/hip_runtime.h>
#include <math.h>

#define NI 100000
#define NO 50000
#define NE 100000
#define NB (NI + NO)          // 150000 combined dst bins
#define TOTE (2 * NE)         // 200000

// ---- ws layout (4B units) ----
#define OFF_WRT_OI    0         // 1024
#define OFF_WRT_IO    1024      // 1024
#define OFF_WFRAG     2048      // 9216 dwords = 2304 uint4: [((rel*9+a)*2+nt)*64+lane]
#define OFF_Y2Z2      11264     // 600000
#define OFF_SCANNED   611264    // 150016 ints
#define OFF_BLOCKSUM  761280    // 640 ints
#define OFF_BLOCKPREF 761920    // 640 ints
#define OFF_SORTED    762560    // 200000 ints
#define OFF_DSTS      962560    // 200000 ints
#define OFF_ACC       1162560   // 4800000 floats (zeroed in k_front)
#define OFF_CNT       5962560   // 150016 ints (memset)
#define OFF_CNT2      6112576   // 150016 ints (memset)
// total ~25 MB

static constexpr int B_EDGE = (NE + 255) / 256;    // 391
static constexpr int B_IND  = (NI + 255) / 256;    // 391
static constexpr int B_ORG  = (NO + 255) / 256;    // 196
static constexpr int SCAN_BLOCKS = (NB + 255) / 256;  // 586

// k_front block ranges
static constexpr int FB_HIST_END  = 782;    // hist (2*B_EDGE)
static constexpr int FB_ZERO_END  = 1038;   // zero acc (256 blocks)
static constexpr int FB_WRT_END   = 1046;   // WrT transposes (8 blocks)
static constexpr int FB_WFRAG_END = 1055;   // weight frags (9 blocks, 2304 threads)

typedef __attribute__((ext_vector_type(8))) short short8;
typedef __attribute__((ext_vector_type(4))) float f32x4;

__device__ __forceinline__ float sigmoidf_fast(float x) {
    return 1.0f / (1.0f + __expf(-x));
}
__device__ __forceinline__ unsigned f2bf(float f) {   // RTNE to bf16 (low 16 bits)
    unsigned u = __float_as_uint(f);
    return (u + 0x7FFFu + ((u >> 16) & 1u)) >> 16;
}
// pack truncated bf16(lo), bf16(hi) into one dword via v_perm
__device__ __forceinline__ unsigned pack_trunc(float lo, float hi) {
    return __builtin_amdgcn_perm(__float_as_uint(hi), __float_as_uint(lo), 0x07060302u);
}

// ---------------------------------------------------------------- fused front-end
__global__ __launch_bounds__(256) void k_front(
    const int* __restrict__ dst_oi, const int* __restrict__ dst_io,
    const float* __restrict__ Wm_oi, const float* __restrict__ bm_oi, const float* __restrict__ Wr_oi,
    const float* __restrict__ Wm_io, const float* __restrict__ bm_io, const float* __restrict__ Wr_io,
    float* __restrict__ ws, int* __restrict__ cnt)
{
    int b = blockIdx.x;
    if (b < FB_HIST_END) {                   // dst histogram
        bool is_io = b >= B_EDGE;
        int e = (is_io ? (b - B_EDGE) : b) * 256 + threadIdx.x;
        if (e >= NE) return;
        int cd = is_io ? (NI + dst_io[e]) : dst_oi[e];
        atomicAdd(&cnt[cd], 1);
    } else if (b < FB_ZERO_END) {            // zero acc
        int idx = (b - FB_HIST_END) * 256 + threadIdx.x;   // [0, 65536)
        float4* a4 = (float4*)(ws + OFF_ACC);
        for (int q = idx; q < 1200000; q += 65536)
            a4[q] = make_float4(0.f, 0.f, 0.f, 0.f);
    } else if (b < FB_WRT_END) {             // WrT transposes
        int u = (b - FB_ZERO_END) * 256 + threadIdx.x;
        if (u < 1024)      ws[OFF_WRT_OI + u] = Wr_oi[(u & 31) * 32 + (u >> 5)];
        else if (u < 2048) { int v = u - 1024; ws[OFF_WRT_IO + v] = Wr_io[(v & 31) * 32 + (v >> 5)]; }
    } else {                                 // MFMA B-fragment prep
        int u = (b - FB_WRT_END) * 256 + threadIdx.x;      // [0, 2304)
        if (u >= 2304) return;
        int rel = u >= 1152;                 // 0 = oi, 1 = io
        int v = u - rel * 1152;
        int lane = v & 63;
        int fi = v >> 6;                     // 0..17
        int a = fi >> 1;                     // 0..8
        int nt = fi & 1;
        int quad = lane >> 4;
        int n = nt * 16 + (lane & 15);
        const float* Wm = rel ? Wm_io : Wm_oi;
        const float* bm = rel ? bm_io : bm_oi;
        unsigned pk[4];
        #pragma unroll
        for (int d = 0; d < 4; d++) {
            int k0 = quad * 8 + 2 * d;
            float vlo = (a < 8) ? Wm[a * 1024 + k0 * 32 + n]       : bm[k0 * 32 + n];
            float vhi = (a < 8) ? Wm[a * 1024 + (k0 + 1) * 32 + n] : bm[(k0 + 1) * 32 + n];
            pk[d] = f2bf(vlo) | (f2bf(vhi) << 16);
        }
        uint4* wf = (uint4*)(ws + OFF_WFRAG);
        wf[((rel * 9 + a) * 2 + nt) * 64 + lane] = make_uint4(pk[0], pk[1], pk[2], pk[3]);
    }
}

// ---------------------------------------------------------------- block-level exclusive scan
__global__ __launch_bounds__(256) void k_scan_block(
    const int* __restrict__ cnt, int* __restrict__ scanned, int* __restrict__ blocksum)
{
    int d = blockIdx.x * 256 + threadIdx.x;
    int v = (d < NB) ? cnt[d] : 0;
    int lane = threadIdx.x & 63, wv = threadIdx.x >> 6;
    int s = v;
    #pragma unroll
    for (int off = 1; off < 64; off <<= 1) {
        int t = __shfl_up(s, off);
        if (lane >= off) s += t;
    }
    __shared__ int wsum[4];
    if (lane == 63) wsum[wv] = s;
    __syncthreads();
    int add = 0;
    for (int w = 0; w < wv; w++) add += wsum[w];
    int incl = s + add;
    scanned[d] = incl - v;
    if (threadIdx.x == 255) blocksum[blockIdx.x] = incl;
}

__global__ __launch_bounds__(1024) void k_scan_top(
    const int* __restrict__ blocksum, int* __restrict__ blockpref)
{
    __shared__ int L[1024];
    int t = threadIdx.x;
    int v = (t < SCAN_BLOCKS) ? blocksum[t] : 0;
    L[t] = v;
    __syncthreads();
    for (int off = 1; off < 1024; off <<= 1) {
        int u = (t >= off) ? L[t - off] : 0;
        __syncthreads();
        L[t] += u;
        __syncthreads();
    }
    if (t < SCAN_BLOCKS) blockpref[t] = L[t] - v;
}

__global__ __launch_bounds__(256) void k_scatter(
    const int* __restrict__ dst_oi, const int* __restrict__ dst_io,
    const int* __restrict__ scanned, const int* __restrict__ blockpref,
    int* __restrict__ cnt2, int* __restrict__ sorted_eid, int* __restrict__ dstsorted)
{
    bool is_io = blockIdx.x >= B_EDGE;
    int e = (is_io ? (blockIdx.x - B_EDGE) : blockIdx.x) * 256 + threadIdx.x;
    if (e >= NE) return;
    int cd = is_io ? (NI + dst_io[e]) : dst_oi[e];
    int base = scanned[cd] + blockpref[cd >> 8];
    int pos = base + atomicAdd(&cnt2[cd], 1);
    sorted_eid[pos] = e;
    dstsorted[pos] = cd;
}

// ---------------------------------------------------------------- layer-1 edge messages via MFMA
__global__ __launch_bounds__(256) void k_edge(
    const int* __restrict__ src_oi, const float* __restrict__ attr_oi,
    const int* __restrict__ src_io, const float* __restrict__ attr_io,
    const float* __restrict__ x_ind, const float* __restrict__ x_org,
    const float* __restrict__ ws,
    const int* __restrict__ sorted_eid, const int* __restrict__ dstsorted,
    float* __restrict__ acc)
{
    __shared__ uint4 xstage[4][256];      // [wave][chunk*64 + row]: 16 KB, bf16 x rows
    __shared__ float stage[256 * 36];     // 36 KB msg staging

    bool is_io = blockIdx.x >= B_EDGE;
    int blockStart = is_io ? (NE + (blockIdx.x - B_EDGE) * 256) : (blockIdx.x * 256);
    int relEnd = is_io ? TOTE : NE;
    int tid = threadIdx.x;
    int wave = tid >> 6, lane = tid & 63, quad = lane >> 4;
    int p = blockStart + tid;
    bool act = p < relEnd;

    const int*   srcA  = is_io ? src_io : src_oi;
    const float* attrA = is_io ? attr_io : attr_oi;
    const float* xsrc  = is_io ? x_ind : x_org;

    // B-fragments (wave-uniform weights), loaded once: 18 frags x uint4
    const uint4* wfr = ((const uint4*)(ws + OFF_WFRAG)) + (is_io ? 1152 : 0);
    uint4 bf[9][2];
    #pragma unroll
    for (int a = 0; a < 9; a++) {
        #pragma unroll
        for (int nt = 0; nt < 2; nt++)
            bf[a][nt] = wfr[((a * 2 + nt) * 64) + lane];
    }

    int cd = -1;
    float ar[9];
    ar[8] = 1.0f;
    if (act) {
        cd = dstsorted[p];
        int e = sorted_eid[p];
        int s = srcA[e];
        {
            const float4* ap = (const float4*)(attrA + e * 8);
            float4 v0 = ap[0], v1 = ap[1];
            ar[0] = v0.x; ar[1] = v0.y; ar[2] = v0.z; ar[3] = v0.w;
            ar[4] = v1.x; ar[5] = v1.y; ar[6] = v1.z; ar[7] = v1.w;
        }
        // stage x row as bf16 (truncated), chunk-major for conflict-free A-frag reads
        const float4* xp = (const float4*)(xsrc + s * 32);
        #pragma unroll
        for (int q = 0; q < 4; q++) {
            float4 v0 = xp[2 * q], v1 = xp[2 * q + 1];
            uint4 pk;
            pk.x = pack_trunc(v0.x, v0.y);
            pk.y = pack_trunc(v0.z, v0.w);
            pk.z = pack_trunc(v1.x, v1.y);
            pk.w = pack_trunc(v1.z, v1.w);
            xstage[wave][q * 64 + lane] = pk;
        }
    }
    // within-wave LDS ordering: reads below see this wave's writes (compiler waits lgkmcnt)

    f32x4 zero4 = {0.f, 0.f, 0.f, 0.f};
    #pragma unroll
    for (int mtile = 0; mtile < 4; mtile++) {
        // A-frag: A[m=lane&15][k=quad*8+j] = bf16 x of edge row (mtile*16 + (lane&15))
        uint4 araw = xstage[wave][quad * 64 + mtile * 16 + (lane & 15)];
        short8 af = *(short8*)&araw;
        float mm0[4] = {0.f, 0.f, 0.f, 0.f};
        float mm1[4] = {0.f, 0.f, 0.f, 0.f};
        #pragma unroll
        for (int a = 0; a < 9; a++) {
            f32x4 t0 = __builtin_amdgcn_mfma_f32_16x16x32_bf16(af, *(short8*)&bf[a][0], zero4, 0, 0, 0);
            f32x4 t1 = __builtin_amdgcn_mfma_f32_16x16x32_bf16(af, *(short8*)&bf[a][1], zero4, 0, 0, 0);
            #pragma unroll
            for (int r = 0; r < 4; r++) {
                int m = mtile * 16 + quad * 4 + r;       // wave-local edge row of this D element
                float av = __shfl(ar[a], m, 64);
                mm0[r] = fmaf(av, t0[r], mm0[r]);
                mm1[r] = fmaf(av, t1[r], mm1[r]);
            }
        }
        // write msg to stage: row = edge-in-block, col = output o
        #pragma unroll
        for (int r = 0; r < 4; r++) {
            int row = wave * 64 + mtile * 16 + quad * 4 + r;
            stage[row * 36 + (lane & 15)]      = mm0[r];
            stage[row * 36 + 16 + (lane & 15)] = mm1[r];
        }
    }
    __syncthreads();

    // phase 2: per-dst segment reduction (sorted dsts -> mostly dense stores)
    bool head = act && (p == blockStart || dstsorted[p - 1] != cd);
    if (head) {
        float msg[32];
        const float4* rrow0 = (const float4*)(stage + tid * 36);
        #pragma unroll
        for (int j = 0; j < 8; j++) {
            float4 v = rrow0[j];
            msg[j * 4 + 0] = v.x; msg[j * 4 + 1] = v.y;
            msg[j * 4 + 2] = v.z; msg[j * 4 + 3] = v.w;
        }
        int blockEnd = min(blockStart + 256, relEnd);
        int q = p + 1;
        while (q < blockEnd && dstsorted[q] == cd) {
            const float4* rrow = (const float4*)(stage + (q - blockStart) * 36);
            #pragma unroll
            for (int j = 0; j < 8; j++) {
                float4 v = rrow[j];
                msg[j * 4 + 0] += v.x; msg[j * 4 + 1] += v.y;
                msg[j * 4 + 2] += v.z; msg[j * 4 + 3] += v.w;
            }
            q++;
        }
        bool openR = (q == blockEnd) && (q < TOTE) && (dstsorted[q] == cd);
        bool openL = (p == blockStart) && (p > 0) && (dstsorted[p - 1] == cd);
        float* dp = acc + (size_t)cd * 32;
        if (openL || openR) {
            #pragma unroll
            for (int o = 0; o < 32; o++) atomicAdd(dp + o, msg[o]);
        } else {
            float4* dp4 = (float4*)dp;
            #pragma unroll
            for (int j = 0; j < 8; j++)
                dp4[j] = make_float4(msg[j * 4 + 0], msg[j * 4 + 1], msg[j * 4 + 2], msg[j * 4 + 3]);
        }
    }
}

// ---------------------------------------------------------------- finish layer 1 + prep layer 2
__global__ __launch_bounds__(256) void k_finish(
    const float* __restrict__ x_ind, const float* __restrict__ x_org,
    const float* __restrict__ ws, const float* __restrict__ acc,
    const float* __restrict__ b_oi, const float* __restrict__ b_io,
    const float* __restrict__ Wm2, const float* __restrict__ bm2,
    const float* __restrict__ Wr2, const float* __restrict__ b2,
    float* __restrict__ y2z2, float* __restrict__ out)
{
    bool is_org = blockIdx.x >= B_IND;
    int n = (is_org ? (blockIdx.x - B_IND) : blockIdx.x) * 256 + threadIdx.x;
    int N = is_org ? NO : NI;
    if (n >= N) return;
    int cd = is_org ? (NI + n) : n;

    const float* x    = is_org ? x_org : x_ind;
    const float* WrT  = ws + (is_org ? OFF_WRT_IO : OFF_WRT_OI);
    const float* bias = is_org ? b_io : b_oi;

    float xr[32];
    const float4* xp = (const float4*)(x + n * 32);
    #pragma unroll
    for (int q = 0; q < 8; q++) {
        float4 v = xp[q];
        xr[q * 4 + 0] = v.x; xr[q * 4 + 1] = v.y; xr[q * 4 + 2] = v.z; xr[q * 4 + 3] = v.w;
    }
    float h[32];
    const float4* aprow = (const float4*)(acc + (size_t)cd * 32);
    #pragma unroll
    for (int q = 0; q < 8; q++) {
        float4 v = aprow[q];
        h[q * 4 + 0] = v.x; h[q * 4 + 1] = v.y; h[q * 4 + 2] = v.z; h[q * 4 + 3] = v.w;
    }
    #pragma unroll 4
    for (int o = 0; o < 32; o++) {
        float s = bias[o] + h[o];
        #pragma unroll
        for (int i = 0; i < 32; i++) s = fmaf(xr[i], WrT[o * 32 + i], s);
        h[o] = sigmoidf_fast(s);
    }
    if (!is_org) {
        float s = b2[0];
        #pragma unroll
        for (int i = 0; i < 32; i++) s = fmaf(h[i], Wr2[i], s);
        out[n] = s;
    } else {
        float z2 = 0.0f;
        #pragma unroll
        for (int i = 0; i < 32; i++) z2 = fmaf(h[i], bm2[i], z2);
        float* yz = y2z2 + n * 12;
        yz[0] = z2;
        #pragma unroll
        for (int a = 0; a < 8; a++) {
            float s = 0.0f;
            #pragma unroll
            for (int i = 0; i < 32; i++) s = fmaf(h[i], Wm2[a * 32 + i], s);
            yz[1 + a] = s;
        }
    }
}

// ---------------------------------------------------------------- layer 2: CSR gather per indivi node
__global__ __launch_bounds__(256) void k_out(
    const int* __restrict__ src_oi, const float* __restrict__ attr_oi,
    const int* __restrict__ scanned, const int* __restrict__ blockpref,
    const int* __restrict__ sorted_eid, const float* __restrict__ y2z2,
    float* __restrict__ out)
{
    int d = blockIdx.x * 256 + threadIdx.x;
    if (d >= NI) return;
    int base = scanned[d] + blockpref[d >> 8];
    int next = scanned[d + 1] + blockpref[(d + 1) >> 8];
    float t = out[d];
    for (int p = base; p < next; p++) {
        int e = sorted_eid[p];
        int s = src_oi[e];
        const float* yz = y2z2 + s * 12;
        const float4* ap = (const float4*)(attr_oi + e * 8);
        float4 a0 = ap[0], a1 = ap[1];
        float m = yz[0];
        m = fmaf(a0.x, yz[1], m); m = fmaf(a0.y, yz[2], m);
        m = fmaf(a0.z, yz[3], m); m = fmaf(a0.w, yz[4], m);
        m = fmaf(a1.x, yz[5], m); m = fmaf(a1.y, yz[6], m);
        m = fmaf(a1.z, yz[7], m); m = fmaf(a1.w, yz[8], m);
        t += m;
    }
    out[d] = sigmoidf_fast(t);
}

// ---------------------------------------------------------------- launch
extern "C" void kernel_launch(void* const* d_in, const int* in_sizes, int n_in,
                              void* d_out, int out_size, void* d_ws, size_t ws_size,
                              hipStream_t stream)
{
    const float* x_ind   = (const float*)d_in[0];
    const float* x_org   = (const float*)d_in[1];
    const int*   src_oi  = (const int*)d_in[2];
    const int*   dst_oi  = (const int*)d_in[3];
    const float* attr_oi = (const float*)d_in[4];
    const int*   src_io  = (const int*)d_in[5];
    const int*   dst_io  = (const int*)d_in[6];
    const float* attr_io = (const float*)d_in[7];
    const float* Wm_oi   = (const float*)d_in[8];
    const float* bm_oi   = (const float*)d_in[9];
    const float* Wr_oi   = (const float*)d_in[10];
    const float* b_oi    = (const float*)d_in[11];
    const float* Wm_io   = (const float*)d_in[12];
    const float* bm_io   = (const float*)d_in[13];
    const float* Wr_io   = (const float*)d_in[14];
    const float* b_io    = (const float*)d_in[15];
    const float* Wm2     = (const float*)d_in[16];
    const float* bm2     = (const float*)d_in[17];
    const float* Wr2     = (const float*)d_in[18];
    const float* b2      = (const float*)d_in[19];

    float* ws        = (float*)d_ws;
    float* y2z2      = ws + OFF_Y2Z2;
    int*   scanned   = (int*)(ws + OFF_SCANNED);
    int*   blocksum  = (int*)(ws + OFF_BLOCKSUM);
    int*   blockpref = (int*)(ws + OFF_BLOCKPREF);
    int*   sorted    = (int*)(ws + OFF_SORTED);
    int*   dsts      = (int*)(ws + OFF_DSTS);
    float* acc       = ws + OFF_ACC;
    int*   cnt       = (int*)(ws + OFF_CNT);
    int*   cnt2      = (int*)(ws + OFF_CNT2);
    float* out       = (float*)d_out;

    // zero cnt + cnt2 (contiguous)
    hipMemsetAsync(ws + OFF_CNT, 0, (size_t)(2 * 150016) * 4, stream);

    k_front<<<FB_WFRAG_END, 256, 0, stream>>>(
        dst_oi, dst_io, Wm_oi, bm_oi, Wr_oi, Wm_io, bm_io, Wr_io, ws, cnt);

    k_scan_block<<<SCAN_BLOCKS, 256, 0, stream>>>(cnt, scanned, blocksum);

    k_scan_top<<<1, 1024, 0, stream>>>(blocksum, blockpref);

    k_scatter<<<2 * B_EDGE, 256, 0, stream>>>(
        dst_oi, dst_io, scanned, blockpref, cnt2, sorted, dsts);

    k_edge<<<2 * B_EDGE, 256, 0, stream>>>(
        src_oi, attr_oi, src_io, attr_io, x_ind, x_org, ws, sorted, dsts, acc);

    k_finish<<<B_IND + B_ORG, 256, 0, stream>>>(
        x_ind, x_org, ws, acc, b_oi, b_io, Wm2, bm2, Wr2, b2, y2z2, out);

    k_out<<<B_IND, 256, 0, stream>>>(
        src_oi, attr_oi, scanned, blockpref, sorted, y2z2, out);
}